// Round 9
// baseline (282.928 us; speedup 1.0000x reference)
//
#include <hip/hip_runtime.h>
#include <hip/hip_bf16.h>

// Hard-batch-mining triplet loss, B=4096, D=2048, NCLS=64, margin=0.3.
// prep (fp32->bf16 + row norms + init) -> gram (SYMMETRIC triangular bf16 MFMA
// GEMM; A direct global->VGPR, B-only LDS, counted-vmcnt single-barrier loop;
// fused distance/mask + dual row/col hardest-pos/neg reduction) -> loss.
// Per-CU step model (R5/R7 measured 3218 cyc): LDS-issue was 2304 cyc (192
// ds_read_b128 x 12). This round: B-only LDS (64 reads -> 768 cyc), A in regs
// (R8-verified pattern, coalesced 64B lines/row, 4x L2 redundancy across the
// wr-sharing waves), R5 8-wave 2x4 geometry (16 waves/CU), R7 counted-vmcnt.
// Loop: stageB(s+1); mfma kk0; loadA kk0(s+1); mfma kk1; loadA kk1(s+1);
//       vmcnt(8)+s_barrier.
//  - vmcnt(8): retires prev iter's 8 A-loads + this iter's 2 stageB (in-order
//    retirement) -> B(s+1) is in LDS before any wave crosses the barrier.
//  - buffer WAR: waves pass the barrier only after their MFMAs issued, and
//    MFMA issue requires lgkmcnt-complete ds_reads of the old buffer.
//  - af0/af1 single-buffered per kk, reloaded right after consumption (WAR is
//    register-dependency-ordered by the compiler); all indices static.

typedef __attribute__((ext_vector_type(8))) short short8;
typedef __attribute__((ext_vector_type(4))) float f32x4;
using bf16 = __hip_bfloat16;

#define BN_ROWS 4096
#define D_DIM   2048
#define TILE    128
#define BK      64
#define NSTEP   (D_DIM / BK)          // 32
#define NB      (BN_ROWS / TILE)      // 32
#define NBLK    (NB * (NB + 1) / 2)   // 528
#define MARGIN  0.3f

__device__ __forceinline__ void gload16(const bf16* g, bf16* l) {
  __builtin_amdgcn_global_load_lds(
      (const __attribute__((address_space(1))) void*)g,
      (__attribute__((address_space(3))) void*)l, 16, 0, 0);
}

// ---------------- prep: convert + row norms + init reductions ----------------
__global__ __launch_bounds__(256) void prep_kernel(
    const float* __restrict__ x, bf16* __restrict__ xb, float* __restrict__ sqv,
    unsigned* __restrict__ pos, unsigned* __restrict__ neg) {
  const int row = blockIdx.x;
  const int t = threadIdx.x;
  const float4* xr = (const float4*)(x + (size_t)row * D_DIM);
  bf16* xbr = xb + (size_t)row * D_DIM;
  float s = 0.f;
  #pragma unroll
  for (int p = 0; p < 2; ++p) {
    const int idx = t + p * 256;  // float4 index, 512 per row; lane-consecutive
    float4 a = xr[idx];
    s += a.x * a.x + a.y * a.y + a.z * a.z + a.w * a.w;
    union { ushort4 v; bf16 h[4]; } u;
    u.h[0] = __float2bfloat16(a.x);
    u.h[1] = __float2bfloat16(a.y);
    u.h[2] = __float2bfloat16(a.z);
    u.h[3] = __float2bfloat16(a.w);
    *(ushort4*)(xbr + (size_t)idx * 4) = u.v;
  }
  #pragma unroll
  for (int o = 32; o; o >>= 1) s += __shfl_down(s, o, 64);
  __shared__ float red[4];
  if ((t & 63) == 0) red[t >> 6] = s;
  __syncthreads();
  if (t == 0) {
    sqv[row] = red[0] + red[1] + red[2] + red[3];
    pos[row] = 0u;           // distances >= 0; diagonal is always same-class
    neg[row] = 0x7F800000u;  // +inf
  }
}

// ---------------- gram: triangular, 8-wave, A-in-regs, B-in-LDS --------------
// 8 waves in 2x4 (wr 0..1, wc 0..3), each wave 64 rows x 32 cols = 4x2
// fragments of 16x16x32. B: LDS [128][64] bf16 per buffer, XOR swizzle
// (c16 ^= row&7) both-sides. A: per-lane global_load_dwordx4 (16 rows x 64B).
__global__ __launch_bounds__(512, 4) void gram_kernel(
    const bf16* __restrict__ xb, const float* __restrict__ sqv,
    const int* __restrict__ tgt, unsigned* __restrict__ pos,
    unsigned* __restrict__ neg) {
  __shared__ bf16 Bs[2][TILE * BK];   // 2 x 16 KiB
  const int t = threadIdx.x;
  const int wave = t >> 6, lane = t & 63;

  // XCD-aware bijective swizzle (528 % 8 == 0): contiguous id range per XCD.
  const int id = (blockIdx.x & 7) * (NBLK / 8) + (blockIdx.x >> 3);

  // triangular decode: id -> (by, bx), bx >= by
  int by = (int)(0.5f * (65.0f - sqrtf(4225.0f - 8.0f * (float)id)));
  while (by * NB - (by * (by - 1)) / 2 > id) --by;
  while ((by + 1) * NB - ((by + 1) * by) / 2 <= id) ++by;
  const int bx = by + (id - (by * NB - (by * (by - 1)) / 2));
  const int rowBase = by * TILE;
  const int colBase = bx * TILE;

  const int wr = wave >> 2, wc = wave & 3;
  const int lhi = lane >> 4, llo = lane & 15;

  f32x4 acc[4][2];
  #pragma unroll
  for (int m = 0; m < 4; ++m)
    #pragma unroll
    for (int n = 0; n < 2; ++n) acc[m][n] = (f32x4){0.f, 0.f, 0.f, 0.f};

  // B staging: 16 chunks of 8 rows; wave w stages chunks {2w, 2w+1}
  const int srow = lane >> 3;         // row within chunk
  const int swz = (lane & 7) ^ srow;  // inverse-swizzled source c16

  auto stageB = [&](int buf, int step) {
    const size_t kcol = (size_t)step * BK + (size_t)swz * 8;
    #pragma unroll
    for (int c = 0; c < 2; ++c) {
      const int chunk = wave * 2 + c;
      gload16(xb + (size_t)(colBase + chunk * 8 + srow) * D_DIM + kcol,
              &Bs[buf][chunk * 512]);
    }
  };

  // A frag (m, kk): lane(llo,lhi) -> row rowBase+wr*64+m*16+llo,
  // k bytes [step*BK + kk*32 + lhi*8, +8): 16 rows x 64B, coalesced.
  auto loadA_kk = [&](int step, int kk, short8* af) {
    const size_t kc = (size_t)step * BK + (size_t)(kk * 32 + lhi * 8);
    #pragma unroll
    for (int m = 0; m < 4; ++m) {
      const int row = rowBase + wr * 64 + m * 16 + llo;
      af[m] = *(const short8*)(xb + (size_t)row * D_DIM + kc);
    }
  };

  auto compute_kk = [&](int buf, int kk, const short8* af) {
    short8 bfr[2];
    #pragma unroll
    for (int n = 0; n < 2; ++n) {
      const int row = wc * 32 + n * 16 + llo;
      const int c16 = (kk * 4 + lhi) ^ (row & 7);
      bfr[n] = *(const short8*)(&Bs[buf][row * 64 + c16 * 8]);
    }
    #pragma unroll
    for (int m = 0; m < 4; ++m)
      #pragma unroll
      for (int n = 0; n < 2; ++n)
        acc[m][n] = __builtin_amdgcn_mfma_f32_16x16x32_bf16(
            af[m], bfr[n], acc[m][n], 0, 0, 0);
  };

  // ---- K-loop: one barrier per step, counted vmcnt, no steady-state drain ----
  short8 af0[4], af1[4];
  stageB(0, 0);
  loadA_kk(0, 0, af0);
  loadA_kk(0, 1, af1);
  asm volatile("s_waitcnt vmcnt(0)\n\ts_barrier" ::: "memory");
  for (int s = 0; s < NSTEP - 1; ++s) {
    stageB((s + 1) & 1, s + 1);       // 2 VMEM; buf (s+1)&1 free since the
                                      // end-of-step-(s-1) barrier
    compute_kk(s & 1, 0, af0);        // MFMA kk0 consumes af0
    loadA_kk(s + 1, 0, af0);          // 4 VMEM; reload af0 (reg-WAR ordered)
    compute_kk(s & 1, 1, af1);
    loadA_kk(s + 1, 1, af1);          // 4 VMEM
    // vmcnt(8): retire prev iter's A-loads + this iter's stageB ->
    // B(s+1) is in LDS; only this iter's 8 A-loads may remain in flight.
    asm volatile("s_waitcnt vmcnt(8)\n\ts_barrier" ::: "memory");
  }
  compute_kk((NSTEP - 1) & 1, 0, af0);  // tail: af loaded in last iteration
  compute_kk((NSTEP - 1) & 1, 1, af1);

  // ---- fused epilogue: distance + class mask + DUAL row/col reductions ----
  // acc layout: col j = colBase+wc*32+n*16+llo, row i = rowBase+wr*64+m*16+lhi*4+r
  const float inf = __uint_as_float(0x7F800000u);
  float sqj[2];
  int tgj[2];
  #pragma unroll
  for (int n = 0; n < 2; ++n) {
    const int j = colBase + wc * 32 + n * 16 + llo;
    sqj[n] = sqv[j];
    tgj[n] = tgt[j];
  }
  float colP[2] = {0.f, 0.f};
  float colN[2] = {inf, inf};

  #pragma unroll
  for (int m = 0; m < 4; ++m) {
    #pragma unroll
    for (int r = 0; r < 4; ++r) {
      const int i = rowBase + wr * 64 + m * 16 + lhi * 4 + r;
      const float sqi = sqv[i];
      const int tgi = tgt[i];
      float pm = 0.0f, nm = inf;
      #pragma unroll
      for (int n = 0; n < 2; ++n) {
        const float g = acc[m][n][r];
        const float d2 = sqi + sqj[n] - 2.0f * g;
        const float d = sqrtf(fmaxf(d2, 1e-12f));
        if (tgj[n] == tgi) {
          pm = fmaxf(pm, d);
          colP[n] = fmaxf(colP[n], d);
        } else {
          nm = fminf(nm, d);
          colN[n] = fminf(colN[n], d);
        }
      }
      #pragma unroll
      for (int o = 1; o < 16; o <<= 1) {
        pm = fmaxf(pm, __shfl_xor(pm, o, 64));
        nm = fminf(nm, __shfl_xor(nm, o, 64));
      }
      if (llo == 0) {
        atomicMax(pos + i, __float_as_uint(pm));  // order-safe: d >= 0
        atomicMin(neg + i, __float_as_uint(nm));
      }
    }
  }
  // col-wise: reduce over lhi (lanes xor 16, 32), then one atomic per col j
  #pragma unroll
  for (int n = 0; n < 2; ++n) {
    float cp = colP[n], cn = colN[n];
    cp = fmaxf(cp, __shfl_xor(cp, 16, 64));
    cp = fmaxf(cp, __shfl_xor(cp, 32, 64));
    cn = fminf(cn, __shfl_xor(cn, 16, 64));
    cn = fminf(cn, __shfl_xor(cn, 32, 64));
    if (lane < 16) {
      const int j = colBase + wc * 32 + n * 16 + llo;
      atomicMax(pos + j, __float_as_uint(cp));
      atomicMin(neg + j, __float_as_uint(cn));
    }
  }
}

// ---------------- loss: mean(relu(d_pos - d_neg + margin)) -------------------
__global__ __launch_bounds__(1024) void loss_kernel(
    const unsigned* __restrict__ pos, const unsigned* __restrict__ neg,
    float* __restrict__ out) {
  const int t = threadIdx.x;
  float s = 0.f;
  for (int i = t; i < BN_ROWS; i += 1024) {
    const float dp = __uint_as_float(pos[i]);
    const float dn = __uint_as_float(neg[i]);
    const float v = dp - dn + MARGIN;
    s += v > 0.f ? v : 0.f;
  }
  #pragma unroll
  for (int o = 32; o; o >>= 1) s += __shfl_down(s, o, 64);
  __shared__ float red[16];
  if ((t & 63) == 0) red[t >> 6] = s;
  __syncthreads();
  if (t < 16) {
    float v = red[t];
    #pragma unroll
    for (int o = 8; o; o >>= 1) v += __shfl_down(v, o, 16);
    if (t == 0) out[0] = v * (1.0f / (float)BN_ROWS);
  }
}

extern "C" void kernel_launch(void* const* d_in, const int* in_sizes, int n_in,
                              void* d_out, int out_size, void* d_ws, size_t ws_size,
                              hipStream_t stream) {
  const float* x = (const float*)d_in[0];
  const int* tgt = (const int*)d_in[1];
  float* out = (float*)d_out;

  char* ws = (char*)d_ws;
  bf16* xb = (bf16*)ws;                                        // 16 MiB
  float* sqv = (float*)(ws + (size_t)BN_ROWS * D_DIM * 2);     // 16 KiB
  unsigned* pos = (unsigned*)((char*)sqv + BN_ROWS * 4);       // 16 KiB
  unsigned* neg = (unsigned*)((char*)pos + BN_ROWS * 4);       // 16 KiB

  prep_kernel<<<BN_ROWS, 256, 0, stream>>>(x, xb, sqv, pos, neg);
  gram_kernel<<<NBLK, 512, 0, stream>>>(xb, sqv, tgt, pos, neg);
  loss_kernel<<<1, 1024, 0, stream>>>(pos, neg, out);
}

// Round 10
// 176.362 us; speedup vs baseline: 1.6042x; 1.6042x over previous
//
#include <hip/hip_runtime.h>
#include <hip/hip_bf16.h>

// Hard-batch-mining triplet loss, B=4096, D=2048, NCLS=64, margin=0.3.
// prep (fp32 -> PACKED-FRAGMENT bf16 + row norms + init) -> gram (SYMMETRIC
// triangular bf16 MFMA GEMM, NO LDS / NO BARRIERS: A and B fragments loaded
// directly global->VGPR as 1KB coalesced wave-loads from the packed layout;
// fused distance/mask + dual row/col hardest-pos/neg reduction) -> loss.
//
// Packed layout: frag f=(g,c), g=row>>4, c=k>>5; element addr
//   xa[((g*64 + c)*64 + lane)*8 .. +8), lane = ((k>>3)&3)*16 + (row&15)
// so a wave's global_load_dwordx4 at (fragbase + lane*16B) yields EXACTLY the
// verified MFMA A/B fragment (lane slice X[g*16+(l&15)][c*32+(l>>4)*8..+8]).
// R9's failure was 16-row gather A-loads; packing makes every frag load a
// single contiguous 1KB wave request. No LDS => the ~3-5k-cyc per-step
// barrier/stage overhead (R2-R9 constant) and the 85%-busy LDS port both
// disappear; new bound = L2 BW (~1.1GB total => ~31us floor).
// Workspace: 16 MiB packed xa + sq[4096] f32 + pos/neg[4096] uint-ordered f32.

typedef __attribute__((ext_vector_type(8))) short short8;
typedef __attribute__((ext_vector_type(4))) float f32x4;
using bf16 = __hip_bfloat16;

#define BN_ROWS 4096
#define D_DIM   2048
#define TILE    128
#define NSTEP   32                    // K-steps of 64 (2 frag-chunks of 32)
#define NB      (BN_ROWS / TILE)      // 32
#define NBLK    (NB * (NB + 1) / 2)   // 528
#define MARGIN  0.3f

// ---------------- prep: convert into packed-frag layout + norms + init -------
// One block per 16-row group g. Thread t: l15 = t&15 (row in group),
// h = t>>4 (0..15); handles chunks idx = h + 16*i (i=0..15) of row g*16+l15.
// xa writes: for fixed i, lanes cover 1KB contiguous (c=4i..4i+3 interleave).
__global__ __launch_bounds__(256) void prep_kernel(
    const float* __restrict__ x, bf16* __restrict__ xa, float* __restrict__ sqv,
    unsigned* __restrict__ pos, unsigned* __restrict__ neg) {
  const int g = blockIdx.x;
  const int t = threadIdx.x;
  const int l15 = t & 15, h = t >> 4;
  const int row = g * 16 + l15;
  const float* xr = x + (size_t)row * D_DIM;
  float s = 0.f;
  #pragma unroll
  for (int i = 0; i < 16; ++i) {
    const int idx = h + 16 * i;                 // chunk of 8 elems, 0..255
    const float4 a = *(const float4*)(xr + idx * 8);
    const float4 b = *(const float4*)(xr + idx * 8 + 4);
    s += a.x * a.x + a.y * a.y + a.z * a.z + a.w * a.w +
         b.x * b.x + b.y * b.y + b.z * b.z + b.w * b.w;
    union { short8 v; bf16 hh[8]; } u;
    u.hh[0] = __float2bfloat16(a.x);
    u.hh[1] = __float2bfloat16(a.y);
    u.hh[2] = __float2bfloat16(a.z);
    u.hh[3] = __float2bfloat16(a.w);
    u.hh[4] = __float2bfloat16(b.x);
    u.hh[5] = __float2bfloat16(b.y);
    u.hh[6] = __float2bfloat16(b.z);
    u.hh[7] = __float2bfloat16(b.w);
    // frag (g, c=idx>>2), lane-slot q*16+l15 with q=idx&3
    *(short8*)(xa + (((size_t)g * 64 + (idx >> 2)) * 64 +
                     (size_t)(idx & 3) * 16 + l15) * 8) = u.v;
  }
  // per-row sum: reduce over h. In-wave: h spans 4 values (lanes +16,+32).
  s += __shfl_down(s, 32, 64);
  s += __shfl_down(s, 16, 64);
  __shared__ float red[4][16];
  if ((t & 63) < 16) red[t >> 6][l15] = s;
  __syncthreads();
  if (t < 16) {
    sqv[g * 16 + t] = red[0][t] + red[1][t] + red[2][t] + red[3][t];
    pos[g * 16 + t] = 0u;           // distances >= 0
    neg[g * 16 + t] = 0x7F800000u;  // +inf
  }
}

// ---------------- gram: triangular, no-LDS streaming MFMA --------------------
// 4 waves in 2x2 (wr, wc), each wave 64x64 = 4x4 fragments of 16x16x32.
// Per K-step(64): 8 A-frag + 8 B-frag loads (1KB coalesced each), 32 MFMA.
// 2-step manual unroll with named cur/nxt frag sets (static indexing).
__global__ __launch_bounds__(256) void gram_kernel(
    const bf16* __restrict__ xa, const float* __restrict__ sqv,
    const int* __restrict__ tgt, unsigned* __restrict__ pos,
    unsigned* __restrict__ neg) {
  const int t = threadIdx.x;
  const int wave = t >> 6, lane = t & 63;

  // XCD-aware bijective swizzle (528 % 8 == 0): contiguous id range per XCD.
  const int id = (blockIdx.x & 7) * (NBLK / 8) + (blockIdx.x >> 3);

  // triangular decode: id -> (by, bx), bx >= by
  int by = (int)(0.5f * (65.0f - sqrtf(4225.0f - 8.0f * (float)id)));
  while (by * NB - (by * (by - 1)) / 2 > id) --by;
  while ((by + 1) * NB - ((by + 1) * by) / 2 <= id) ++by;
  const int bx = by + (id - (by * NB - (by * (by - 1)) / 2));
  const int rowBase = by * TILE;
  const int colBase = bx * TILE;

  const int wr = wave >> 1, wc = wave & 1;
  const int lhi = lane >> 4, llo = lane & 15;

  // frag base pointers: frag (g, c) at xa + ((g*64 + c)*64 + lane)*8 elems
  const int gA0 = (rowBase >> 4) + wr * 4;   // A row-groups gA0..gA0+3
  const int gB0 = (colBase >> 4) + wc * 4;   // B col-groups
  const bf16* baseA[4];
  const bf16* baseB[4];
  #pragma unroll
  for (int m = 0; m < 4; ++m) {
    baseA[m] = xa + ((size_t)(gA0 + m) * 4096 + (size_t)lane * 8);
    baseB[m] = xa + ((size_t)(gB0 + m) * 4096 + (size_t)lane * 8);
  }

  f32x4 acc[4][4];
  #pragma unroll
  for (int m = 0; m < 4; ++m)
    #pragma unroll
    for (int n = 0; n < 4; ++n) acc[m][n] = (f32x4){0.f, 0.f, 0.f, 0.f};

  short8 afA[8], bfA[8], afB[8], bfB[8];  // [m*2+kk] / [n*2+kk]

  auto loadStep = [&](int s, short8* af, short8* bf) {
    const size_t co = (size_t)s * 1024;   // c = 2s -> offset 2s*512 elems
    #pragma unroll
    for (int m = 0; m < 4; ++m) {
      af[m * 2 + 0] = *(const short8*)(baseA[m] + co);
      af[m * 2 + 1] = *(const short8*)(baseA[m] + co + 512);
      bf[m * 2 + 0] = *(const short8*)(baseB[m] + co);
      bf[m * 2 + 1] = *(const short8*)(baseB[m] + co + 512);
    }
  };
  auto mfmaStep = [&](const short8* af, const short8* bf) {
    #pragma unroll
    for (int kk = 0; kk < 2; ++kk)
      #pragma unroll
      for (int m = 0; m < 4; ++m)
        #pragma unroll
        for (int n = 0; n < 4; ++n)
          acc[m][n] = __builtin_amdgcn_mfma_f32_16x16x32_bf16(
              af[m * 2 + kk], bf[n * 2 + kk], acc[m][n], 0, 0, 0);
  };

  // ---- barrier-free K-loop: frags double-buffered in registers ----
  loadStep(0, afA, bfA);
  for (int s = 0; s < NSTEP; s += 2) {
    if (s + 1 < NSTEP) loadStep(s + 1, afB, bfB);   // prefetch odd step
    mfmaStep(afA, bfA);                              // compute even step
    if (s + 2 < NSTEP) loadStep(s + 2, afA, bfA);   // prefetch next even
    if (s + 1 < NSTEP) mfmaStep(afB, bfB);          // compute odd step
  }

  // ---- fused epilogue: distance + class mask + DUAL row/col reductions ----
  // acc layout: col j = colBase+wc*64+n*16+llo, row i = rowBase+wr*64+m*16+lhi*4+r
  const float inf = __uint_as_float(0x7F800000u);
  float sqj[4];
  int tgj[4];
  #pragma unroll
  for (int n = 0; n < 4; ++n) {
    const int j = colBase + wc * 64 + n * 16 + llo;
    sqj[n] = sqv[j];
    tgj[n] = tgt[j];
  }
  float colP[4] = {0.f, 0.f, 0.f, 0.f};
  float colN[4] = {inf, inf, inf, inf};

  #pragma unroll
  for (int m = 0; m < 4; ++m) {
    #pragma unroll
    for (int r = 0; r < 4; ++r) {
      const int i = rowBase + wr * 64 + m * 16 + lhi * 4 + r;
      const float sqi = sqv[i];
      const int tgi = tgt[i];
      float pm = 0.0f, nm = inf;
      #pragma unroll
      for (int n = 0; n < 4; ++n) {
        const float g = acc[m][n][r];
        const float d2 = sqi + sqj[n] - 2.0f * g;
        const float d = sqrtf(fmaxf(d2, 1e-12f));
        if (tgj[n] == tgi) {
          pm = fmaxf(pm, d);
          colP[n] = fmaxf(colP[n], d);
        } else {
          nm = fminf(nm, d);
          colN[n] = fminf(colN[n], d);
        }
      }
      #pragma unroll
      for (int o = 1; o < 16; o <<= 1) {
        pm = fmaxf(pm, __shfl_xor(pm, o, 64));
        nm = fminf(nm, __shfl_xor(nm, o, 64));
      }
      if (llo == 0) {
        atomicMax(pos + i, __float_as_uint(pm));  // order-safe: d >= 0
        atomicMin(neg + i, __float_as_uint(nm));
      }
    }
  }
  // col-wise: reduce over lhi (lanes xor 16, 32), then one atomic per col j
  #pragma unroll
  for (int n = 0; n < 4; ++n) {
    float cp = colP[n], cn = colN[n];
    cp = fmaxf(cp, __shfl_xor(cp, 16, 64));
    cp = fmaxf(cp, __shfl_xor(cp, 32, 64));
    cn = fminf(cn, __shfl_xor(cn, 16, 64));
    cn = fminf(cn, __shfl_xor(cn, 32, 64));
    if (lane < 16) {
      const int j = colBase + wc * 64 + n * 16 + llo;
      atomicMax(pos + j, __float_as_uint(cp));
      atomicMin(neg + j, __float_as_uint(cn));
    }
  }
}

// ---------------- loss: mean(relu(d_pos - d_neg + margin)) -------------------
__global__ __launch_bounds__(1024) void loss_kernel(
    const unsigned* __restrict__ pos, const unsigned* __restrict__ neg,
    float* __restrict__ out) {
  const int t = threadIdx.x;
  float s = 0.f;
  for (int i = t; i < BN_ROWS; i += 1024) {
    const float dp = __uint_as_float(pos[i]);
    const float dn = __uint_as_float(neg[i]);
    const float v = dp - dn + MARGIN;
    s += v > 0.f ? v : 0.f;
  }
  #pragma unroll
  for (int o = 32; o; o >>= 1) s += __shfl_down(s, o, 64);
  __shared__ float red[16];
  if ((t & 63) == 0) red[t >> 6] = s;
  __syncthreads();
  if (t < 16) {
    float v = red[t];
    #pragma unroll
    for (int o = 8; o; o >>= 1) v += __shfl_down(v, o, 16);
    if (t == 0) out[0] = v * (1.0f / (float)BN_ROWS);
  }
}

extern "C" void kernel_launch(void* const* d_in, const int* in_sizes, int n_in,
                              void* d_out, int out_size, void* d_ws, size_t ws_size,
                              hipStream_t stream) {
  const float* x = (const float*)d_in[0];
  const int* tgt = (const int*)d_in[1];
  float* out = (float*)d_out;

  char* ws = (char*)d_ws;
  bf16* xa = (bf16*)ws;                                        // 16 MiB packed
  float* sqv = (float*)(ws + (size_t)BN_ROWS * D_DIM * 2);     // 16 KiB
  unsigned* pos = (unsigned*)((char*)sqv + BN_ROWS * 4);       // 16 KiB
  unsigned* neg = (unsigned*)((char*)pos + BN_ROWS * 4);       // 16 KiB

  prep_kernel<<<BN_ROWS / 16, 256, 0, stream>>>(x, xa, sqv, pos, neg);
  gram_kernel<<<NBLK, 256, 0, stream>>>(xa, sqv, tgt, pos, neg);
  loss_kernel<<<1, 1024, 0, stream>>>(pos, neg, out);
}